// Round 8
// baseline (102.688 us; speedup 1.0000x reference)
//
#include <hip/hip_runtime.h>

typedef float fx4 __attribute__((ext_vector_type(4)));
typedef short s16x8 __attribute__((ext_vector_type(8)));
typedef __bf16 bfx8 __attribute__((ext_vector_type(8)));

#define KN 1024
#define TT 16384
#define NOUT 16382
#define NKT 32   // K' = 2048, tiles of 64

// ws layout: Apk (4 MiB) at 0; B1 bitmasks after
#define B1_OFF 4194304u

__device__ __forceinline__ unsigned short f2bf(float f) {
  return __builtin_bit_cast(unsigned short, (__bf16)f);
}

__device__ __forceinline__ void gll16(const void* g, void* l) {
  __builtin_amdgcn_global_load_lds(
      (const __attribute__((address_space(1))) void*)g,
      (__attribute__((address_space(3))) void*)l, 16, 0, 0);
}

// ---- kernel 1: adjacency bitmask rows (1024 bits = 32 u32 per node) ----
__global__ __launch_bounds__(256) void k_masks(const float* __restrict__ A,
                                               unsigned* __restrict__ B1) {
  int k = blockIdx.x;
  int tid = threadIdx.x;
  int wv = tid >> 6, lane = tid & 63;
  for (int i = 0; i < 4; ++i) {
    int n = i * 256 + wv * 64 + lane;
    bool bit = (A[(size_t)k * KN + n] > 0.5f) && (n != k);
    unsigned long long m = __ballot(bit);
    if (lane == 0) {
      B1[k * 32 + i * 8 + wv * 2]     = (unsigned)m;
      B1[k * 32 + i * 8 + wv * 2 + 1] = (unsigned)(m >> 32);
    }
  }
}

// ---- kernel 2: build interleaved Wc (bf16) pre-packed in MFMA A-tile layout ----
// k' = 2n + s: s=0 -> coeffs idx0 (pairs with X[.,j+1]), s=1 -> coeffs idx1 (X[.,j])
__global__ __launch_bounds__(256) void k_weights(const unsigned* __restrict__ B1,
                                                 const float* __restrict__ alpha,
                                                 const float* __restrict__ beta0,
                                                 const float* __restrict__ beta1,
                                                 unsigned short* __restrict__ Wc) {
  __shared__ unsigned reach[32];
  __shared__ unsigned ex2[32];
  __shared__ unsigned short list[1056];
  __shared__ int nl;
  int k = blockIdx.x, tid = threadIdx.x;
  if (tid == 0) nl = 0;
  if (tid < 32) {
    unsigned r = B1[k * 32 + tid];
    if (tid == (k >> 5)) r |= 1u << (k & 31);  // reach = {k} | N(k)
    reach[tid] = r;
    ex2[tid] = 0;
  }
  __syncthreads();
  for (int m = tid; m < KN; m += 256)
    if ((reach[m >> 5] >> (m & 31)) & 1) {
      int i = atomicAdd(&nl, 1);
      list[i] = (unsigned short)m;
    }
  __syncthreads();
  int n2 = nl;
  for (int i = 0; i < n2; ++i) {
    int m = list[i];
    if (tid < 32) ex2[tid] |= B1[m * 32 + tid];   // union of N(m), m in reach
  }
  __syncthreads();
  if (tid < 32) ex2[tid] &= ~reach[tid];          // distance exactly 2
  __syncthreads();
  int d1 = 0, d2 = 0;
  for (int w = 0; w < 32; ++w) { d1 += __popc(reach[w]); d2 += __popc(ex2[w]); }
  d1 -= 1;  // remove self bit
  float rd1 = 1.0f / fmaxf((float)d1, 1.0f);
  float rd2 = 1.0f / fmaxf((float)d2, 1.0f);
  float c00 = beta0[0] * rd1, c01 = beta0[1] * rd1;
  float c10 = beta1[0] * rd2, c11 = beta1[1] * rd2;
  float a0 = alpha[0], a1 = alpha[1];
  int mb = k >> 8, rloc = k & 255;
  for (int q = 0; q < 4; ++q) {
    int n = tid * 4 + q;
    bool in1 = (((reach[n >> 5] >> (n & 31)) & 1) != 0) && (n != k);
    bool in2 = ((ex2[n >> 5] >> (n & 31)) & 1) != 0;
    float v0 = (in1 ? c00 : 0.f) + (in2 ? c10 : 0.f) + (n == k ? a0 : 0.f);
    float v1 = (in1 ? c01 : 0.f) + (in2 ? c11 : 0.f) + (n == k ? a1 : 0.f);
    int kt = n >> 5, qk = (n >> 4) & 1, kb = (n >> 2) & 3, ii = (n & 3) * 2;
    size_t idx = ((((size_t)(mb * 32 + kt) * 2 + qk) * 4 + kb) * 256 + rloc) * 8 + ii;
    unsigned pair = (unsigned)f2bf(v0) | ((unsigned)f2bf(v1) << 16);
    *reinterpret_cast<unsigned*>(Wc + idx) = pair;
  }
}

// ---- kernel 3: fused 256x256 GEMM; B packed from f32 X in-kernel ----
// 8 waves (2M x 4N), 4 phases/K-tile, frag double-buffer, counted vmcnt.
// A via gll16 (pre-packed Apk); B: X -> reg (16 dword) -> cvt/interleave ->
// ds_write_b128, producing the identical LDS image the old pack produced.
__global__ __launch_bounds__(512, 2) void k_gemm(const char* __restrict__ Apk,
                                                 const float* __restrict__ X,
                                                 float* __restrict__ Y) {
  __shared__ char lds[131072];  // 2 buf x { A 32K (h0|h1) | B 32K (h0|h1) }
  int bid = blockIdx.x;
  int swz = (bid & 7) * 32 + (bid >> 3);   // XCD-contiguous work chunks
  int jb = swz >> 2, mb = swz & 3;
  int tid = threadIdx.x;
  int lane = tid & 63, wv = tid >> 6;
  int wm = wv >> 2, wn = wv & 3;           // wave out: rows wm*128, cols wn*64
  int kb = lane >> 4, ml = lane & 15;
  const char* Asrc = Apk + (size_t)mb * (NKT * 32768);

  // B-staging thread geometry: dests u=tid (kbq=tid>>8) and u=tid+512 (kbq+2)
  int col = tid & 255;
  int kbq = tid >> 8;                      // 0..1
  int j = jb * 256 + col;
  bool jlast = (j == TT - 1);
  int jx = jlast ? (TT - 2) : j;           // clamped base; always jx+1 valid

  fx4 acc[2][4][4];
#pragma unroll
  for (int q = 0; q < 2; ++q)
#pragma unroll
    for (int a = 0; a < 4; ++a)
#pragma unroll
      for (int b = 0; b < 4; ++b) acc[q][a][b] = (fx4){0.f, 0.f, 0.f, 0.f};

  auto stage_A = [&](int tile, int qh) {   // 2 gll16
    char* dst = lds + (tile & 1) * 65536 + qh * 16384;
    const char* src = Asrc + ((size_t)(tile & (NKT - 1)) * 2 + qh) * 16384;
    gll16(src + tid * 16, dst + tid * 16);
    gll16(src + (size_t)(tid + 512) * 16, dst + (tid + 512) * 16);
  };

  // issue 16 dword loads for B half (tile t, k-half qh)
#define BLOAD(ra, rb, t, qh)                                                        \
  do {                                                                              \
    int mq_ = ((t) & (NKT - 1)) * 32 + (qh) * 16 + kbq * 4;                         \
    _Pragma("unroll") for (int p = 0; p < 4; ++p) {                                 \
      const float* xp_ = X + (size_t)(mq_ + p) * TT + jx;                           \
      ra[p] = xp_[0]; rb[p] = xp_[1];                                               \
      const float* xq_ = X + (size_t)(mq_ + 8 + p) * TT + jx;                       \
      ra[4 + p] = xq_[0]; rb[4 + p] = xq_[1];                                       \
    }                                                                               \
  } while (0)
  // convert + interleave + 2 ds_write_b128 (dest image == old Bpk bytes)
#define BWRITE(ra, rb, t, qh)                                                       \
  do {                                                                              \
    char* db_ = lds + ((t) & 1) * 65536 + 32768 + (qh) * 16384 + tid * 16;          \
    uint4 w0_, w1_;                                                                 \
    unsigned pr_[8];                                                                \
    _Pragma("unroll") for (int p = 0; p < 8; ++p) {                                 \
      float f1_ = jlast ? rb[p] : ra[p];     /* X[m, j]   (s=1, hi) */              \
      float f0_ = jlast ? 0.f : rb[p];       /* X[m, j+1] (s=0, lo) */              \
      pr_[p] = (unsigned)f2bf(f0_) | ((unsigned)f2bf(f1_) << 16);                   \
    }                                                                               \
    w0_.x = pr_[0]; w0_.y = pr_[1]; w0_.z = pr_[2]; w0_.w = pr_[3];                 \
    w1_.x = pr_[4]; w1_.y = pr_[5]; w1_.z = pr_[6]; w1_.w = pr_[7];                 \
    *reinterpret_cast<uint4*>(db_) = w0_;                                           \
    *reinterpret_cast<uint4*>(db_ + 8192) = w1_;                                    \
  } while (0)
#define READ_A(dst, t, qk, qm)                                                      \
  do {                                                                              \
    const char* Ah_ = lds + ((t) & 1) * 65536 + (qk) * 16384;                       \
    _Pragma("unroll") for (int mf = 0; mf < 4; ++mf)                                \
      dst[mf] = *(const s16x8*)(Ah_ +                                               \
          (size_t)(kb * 256 + wm * 128 + (qm) * 64 + mf * 16 + ml) * 16);           \
  } while (0)
#define READ_B(dst, t, qk)                                                          \
  do {                                                                              \
    const char* Bh_ = lds + ((t) & 1) * 65536 + 32768 + (qk) * 16384;               \
    _Pragma("unroll") for (int nf = 0; nf < 4; ++nf)                                \
      dst[nf] = *(const s16x8*)(Bh_ +                                               \
          (size_t)(kb * 256 + wn * 64 + nf * 16 + ml) * 16);                        \
  } while (0)
#define MFMA16(acc_, a_, b_)                                                        \
  do {                                                                              \
    __builtin_amdgcn_s_setprio(1);                                                  \
    _Pragma("unroll") for (int mf = 0; mf < 4; ++mf)                                \
      _Pragma("unroll") for (int nf = 0; nf < 4; ++nf)                              \
        acc_[mf][nf] = __builtin_amdgcn_mfma_f32_16x16x32_bf16(                     \
            __builtin_bit_cast(bfx8, a_[mf]), __builtin_bit_cast(bfx8, b_[nf]),     \
            acc_[mf][nf], 0, 0, 0);                                                 \
    __builtin_amdgcn_s_setprio(0);                                                  \
  } while (0)

  s16x8 aA[4], aB[4], bA[4], bB[4];
  float ra0[8], rb0[8], ra1[8], rb1[8], ra[8], rb[8];

  // prologue: [B16,A2] x3 = 30 outstanding; ladder drains each B16 before write
  BLOAD(ra0, rb0, 0, 0); stage_A(0, 0);
  BLOAD(ra1, rb1, 0, 1); stage_A(0, 1);
  BLOAD(ra, rb, 1, 0);   stage_A(1, 0);
  asm volatile("s_waitcnt vmcnt(38)" ::: "memory");
  BWRITE(ra0, rb0, 0, 0);
  asm volatile("s_waitcnt vmcnt(20)" ::: "memory");
  BWRITE(ra1, rb1, 0, 1);
  asm volatile("s_waitcnt vmcnt(2)" ::: "memory");
  BWRITE(ra, rb, 1, 0);
  asm volatile("s_waitcnt lgkmcnt(0)" ::: "memory");
  __builtin_amdgcn_s_barrier();
  READ_A(aA, 0, 0, 0);
  READ_B(bA, 0, 0);

  for (int kt = 0; kt < NKT; ++kt) {
    // p0: MFMA(aA,bA); prefetch aB<-A(kt,h1); issue B(kt+1,h1) loads; stage A h1(kt+1)
    READ_A(aB, kt, 0, 1);
    BLOAD(ra, rb, kt + 1, 1);
    stage_A(kt + 1, 1);
    MFMA16(acc[0], aA, bA);
    // p1: MFMA(aB,bA); prefetch aA<-A(kt,h1... qk1), bB<-B(kt,h1); write B(kt+1,h1)
    READ_A(aA, kt, 1, 0);
    READ_B(bB, kt, 1);
    MFMA16(acc[1], aB, bA);
    asm volatile("s_waitcnt vmcnt(2)" ::: "memory");   // drains B16(p0) + prior A2
    BWRITE(ra, rb, kt + 1, 1);
    asm volatile("s_waitcnt lgkmcnt(0)" ::: "memory");
    __builtin_amdgcn_s_barrier();
    // p2: MFMA(aA,bB); prefetch aB; issue B(kt+2,h0) loads; stage A h0(kt+2)
    READ_A(aB, kt, 1, 1);
    BLOAD(ra, rb, kt + 2, 0);
    stage_A(kt + 2, 0);
    MFMA16(acc[0], aA, bB);
    // p3: MFMA(aB,bB); prefetch aA<-A(kt+1,h0), bA<-B(kt+1,h0); write B(kt+2,h0)
    READ_A(aA, kt + 1, 0, 0);
    READ_B(bA, kt + 1, 0);
    MFMA16(acc[1], aB, bB);
    asm volatile("s_waitcnt vmcnt(2)" ::: "memory");   // drains B16(p2) + A2(p0)
    BWRITE(ra, rb, kt + 2, 0);
    asm volatile("s_waitcnt lgkmcnt(0)" ::: "memory");
    __builtin_amdgcn_s_barrier();
  }
  asm volatile("s_waitcnt vmcnt(0)" ::: "memory");

  // epilogue: C/D layout col=lane&15, row=(lane>>4)*4+r
  int c0 = jb * 256 + wn * 64;
  int r0 = mb * 256 + wm * 128;
#pragma unroll
  for (int qm = 0; qm < 2; ++qm)
#pragma unroll
    for (int mf = 0; mf < 4; ++mf)
#pragma unroll
      for (int nf = 0; nf < 4; ++nf) {
        int c = c0 + nf * 16 + ml;
        if (c < NOUT) {
          int r = r0 + qm * 64 + mf * 16 + (lane >> 4) * 4;
#pragma unroll
          for (int i = 0; i < 4; ++i)
            Y[(size_t)(r + i) * NOUT + c] = acc[qm][mf][nf][i];
        }
      }
#undef BLOAD
#undef BWRITE
#undef READ_A
#undef READ_B
#undef MFMA16
}

extern "C" void kernel_launch(void* const* d_in, const int* in_sizes, int n_in,
                              void* d_out, int out_size, void* d_ws, size_t ws_size,
                              hipStream_t stream) {
  const float* X     = (const float*)d_in[0];
  const float* A     = (const float*)d_in[1];
  const float* alpha = (const float*)d_in[2];
  const float* beta0 = (const float*)d_in[3];
  const float* beta1 = (const float*)d_in[4];
  float* Y = (float*)d_out;
  char* ws = (char*)d_ws;
  char* Apk = ws;                       // 4 MiB
  unsigned* B1 = (unsigned*)(ws + B1_OFF);

  k_masks<<<dim3(1024), dim3(256), 0, stream>>>(A, B1);
  k_weights<<<dim3(1024), dim3(256), 0, stream>>>(B1, alpha, beta0, beta1,
                                                  (unsigned short*)Apk);
  k_gemm<<<dim3(256), dim3(512), 0, stream>>>(Apk, X, Y);
}

// Round 9
// 91.447 us; speedup vs baseline: 1.1229x; 1.1229x over previous
//
#include <hip/hip_runtime.h>

typedef float fx4 __attribute__((ext_vector_type(4)));
typedef short s16x8 __attribute__((ext_vector_type(8)));
typedef __bf16 bfx8 __attribute__((ext_vector_type(8)));

#define KN 1024
#define TT 16384
#define NOUT 16382
#define NKT 32   // K' = 2048, tiles of 64

// ws layout: Bpk (64 MiB) at 0; Apk (4 MiB); B1 bitmasks (128 KiB)
#define APK_OFF 67108864u
#define B1_OFF  (APK_OFF + 4194304u)

__device__ __forceinline__ unsigned short f2bf(float f) {
  return __builtin_bit_cast(unsigned short, (__bf16)f);
}

__device__ __forceinline__ void gll16(const void* g, void* l) {
  __builtin_amdgcn_global_load_lds(
      (const __attribute__((address_space(1))) void*)g,
      (__attribute__((address_space(3))) void*)l, 16, 0, 0);
}

// ---- kernel 1: adjacency bitmask rows (1024 bits = 32 u32 per node) ----
__global__ __launch_bounds__(256) void k_masks(const float* __restrict__ A,
                                               unsigned* __restrict__ B1) {
  int k = blockIdx.x;
  int tid = threadIdx.x;
  int wv = tid >> 6, lane = tid & 63;
  for (int i = 0; i < 4; ++i) {
    int n = i * 256 + wv * 64 + lane;
    bool bit = (A[(size_t)k * KN + n] > 0.5f) && (n != k);
    unsigned long long m = __ballot(bit);
    if (lane == 0) {
      B1[k * 32 + i * 8 + wv * 2]     = (unsigned)m;
      B1[k * 32 + i * 8 + wv * 2 + 1] = (unsigned)(m >> 32);
    }
  }
}

// ---- kernel 2 (fused): blocks 0-1023 build Wc; blocks 1024+ pack X2 ----
// Wc: k' = 2n + s (s=0 pairs X[.,j+1], s=1 pairs X[.,j]), MFMA A-tile layout
//   idx = ((((mb*32+kt)*2+qk)*4+kb)*256 + rloc)*8 + ii
// X2 pack: G = ((((jb*32+kt)*2+qk)*4+kb)*256 + col), elem ii interleaves lag pair
__global__ __launch_bounds__(256) void k_wp(const unsigned* __restrict__ B1,
                                            const float* __restrict__ alpha,
                                            const float* __restrict__ beta0,
                                            const float* __restrict__ beta1,
                                            const float* __restrict__ X,
                                            unsigned short* __restrict__ Wc,
                                            unsigned short* __restrict__ Bpk) {
  int tid = threadIdx.x;
  if (blockIdx.x >= 1024) {
    // ---------------- pack path ----------------
    int G = (blockIdx.x - 1024) * 256 + tid;   // 0 .. 4,194,303
    int col = G & 255;
    int kb  = (G >> 8) & 3;
    int qk  = (G >> 10) & 1;
    int kt  = (G >> 11) & 31;
    int jb  = G >> 16;
    int j   = jb * 256 + col;
    int mbase = kt * 32 + qk * 16 + kb * 4;
    unsigned v[4];
#pragma unroll
    for (int p = 0; p < 4; ++p) {
      int m = mbase + p;
      int j1 = j + 1;
      float f0 = (j1 < TT) ? X[(size_t)m * TT + j1] : 0.0f;  // s=0
      float f1 = X[(size_t)m * TT + j];                      // s=1
      v[p] = (unsigned)f2bf(f0) | ((unsigned)f2bf(f1) << 16);
    }
    uint4 w; w.x = v[0]; w.y = v[1]; w.z = v[2]; w.w = v[3];
    *reinterpret_cast<uint4*>(Bpk + (size_t)G * 8) = w;
    return;
  }
  // ---------------- weights path ----------------
  __shared__ unsigned reach[32];
  __shared__ unsigned ex2[32];
  __shared__ unsigned short list[1056];
  __shared__ int nl;
  int k = blockIdx.x;
  if (tid == 0) nl = 0;
  if (tid < 32) {
    unsigned r = B1[k * 32 + tid];
    if (tid == (k >> 5)) r |= 1u << (k & 31);  // reach = {k} | N(k)
    reach[tid] = r;
    ex2[tid] = 0;
  }
  __syncthreads();
  for (int m = tid; m < KN; m += 256)
    if ((reach[m >> 5] >> (m & 31)) & 1) {
      int i = atomicAdd(&nl, 1);
      list[i] = (unsigned short)m;
    }
  __syncthreads();
  int n2 = nl;
  for (int i = 0; i < n2; ++i) {
    int m = list[i];
    if (tid < 32) ex2[tid] |= B1[m * 32 + tid];   // union of N(m), m in reach
  }
  __syncthreads();
  if (tid < 32) ex2[tid] &= ~reach[tid];          // distance exactly 2
  __syncthreads();
  int d1 = 0, d2 = 0;
  for (int w = 0; w < 32; ++w) { d1 += __popc(reach[w]); d2 += __popc(ex2[w]); }
  d1 -= 1;  // remove self bit
  float rd1 = 1.0f / fmaxf((float)d1, 1.0f);
  float rd2 = 1.0f / fmaxf((float)d2, 1.0f);
  float c00 = beta0[0] * rd1, c01 = beta0[1] * rd1;
  float c10 = beta1[0] * rd2, c11 = beta1[1] * rd2;
  float a0 = alpha[0], a1 = alpha[1];
  int mb = k >> 8, rloc = k & 255;
  for (int q = 0; q < 4; ++q) {
    int n = tid * 4 + q;
    bool in1 = (((reach[n >> 5] >> (n & 31)) & 1) != 0) && (n != k);
    bool in2 = ((ex2[n >> 5] >> (n & 31)) & 1) != 0;
    float v0 = (in1 ? c00 : 0.f) + (in2 ? c10 : 0.f) + (n == k ? a0 : 0.f);
    float v1 = (in1 ? c01 : 0.f) + (in2 ? c11 : 0.f) + (n == k ? a1 : 0.f);
    int kt = n >> 5, qk = (n >> 4) & 1, kb = (n >> 2) & 3, ii = (n & 3) * 2;
    size_t idx = ((((size_t)(mb * 32 + kt) * 2 + qk) * 4 + kb) * 256 + rloc) * 8 + ii;
    unsigned pair = (unsigned)f2bf(v0) | ((unsigned)f2bf(v1) << 16);
    *reinterpret_cast<unsigned*>(Wc + idx) = pair;
  }
}

// ---- kernel 3: 256x256 pipelined GEMM, K'=2048 (R6, best known) ----
// 4 phases/K-tile, frag register double-buffer; barrier+vmcnt(4) only at
// end of p1/p3 (loads span barriers, T3/T4); no sched_barrier pins.
__global__ __launch_bounds__(512, 2) void k_gemm(const char* __restrict__ Apk,
                                                 const char* __restrict__ Bpk,
                                                 float* __restrict__ Y) {
  __shared__ char lds[131072];  // 2 buf x { A 32K (h0|h1) | B 32K (h0|h1) }
  int bid = blockIdx.x;
  int swz = (bid & 7) * 32 + (bid >> 3);   // XCD-contiguous work chunks
  int jb = swz >> 2, mb = swz & 3;
  int tid = threadIdx.x;
  int lane = tid & 63, wv = tid >> 6;
  int wm = wv >> 2, wn = wv & 3;           // wave out: rows wm*128, cols wn*64
  int kb = lane >> 4, ml = lane & 15;
  const char* Asrc = Apk + (size_t)mb * (NKT * 2 * 16384);
  const char* Bsrc = Bpk + (size_t)jb * (NKT * 2 * 16384);

  fx4 acc[2][4][4];
#pragma unroll
  for (int q = 0; q < 2; ++q)
#pragma unroll
    for (int a = 0; a < 4; ++a)
#pragma unroll
      for (int b = 0; b < 4; ++b) acc[q][a][b] = (fx4){0.f, 0.f, 0.f, 0.f};

  auto stage_half = [&](int tile, int isB, int qh) {
    char* dst = lds + (tile & 1) * 65536 + isB * 32768 + qh * 16384;
    const char* src = (isB ? Bsrc : Asrc) + ((size_t)(tile & (NKT - 1)) * 2 + qh) * 16384;
    gll16(src + tid * 16, dst + tid * 16);
    gll16(src + (size_t)(tid + 512) * 16, dst + (tid + 512) * 16);
  };

#define READ_A(dst, t, qk, qm)                                                      \
  do {                                                                              \
    const char* Ah_ = lds + ((t) & 1) * 65536 + (qk) * 16384;                       \
    _Pragma("unroll") for (int mf = 0; mf < 4; ++mf)                                \
      dst[mf] = *(const s16x8*)(Ah_ +                                               \
          (size_t)(kb * 256 + wm * 128 + (qm) * 64 + mf * 16 + ml) * 16);           \
  } while (0)
#define READ_B(dst, t, qk)                                                          \
  do {                                                                              \
    const char* Bh_ = lds + ((t) & 1) * 65536 + 32768 + (qk) * 16384;               \
    _Pragma("unroll") for (int nf = 0; nf < 4; ++nf)                                \
      dst[nf] = *(const s16x8*)(Bh_ +                                               \
          (size_t)(kb * 256 + wn * 64 + nf * 16 + ml) * 16);                        \
  } while (0)
#define MFMA16(acc_, a_, b_)                                                        \
  do {                                                                              \
    __builtin_amdgcn_s_setprio(1);                                                  \
    _Pragma("unroll") for (int mf = 0; mf < 4; ++mf)                                \
      _Pragma("unroll") for (int nf = 0; nf < 4; ++nf)                              \
        acc_[mf][nf] = __builtin_amdgcn_mfma_f32_16x16x32_bf16(                     \
            __builtin_bit_cast(bfx8, a_[mf]), __builtin_bit_cast(bfx8, b_[nf]),     \
            acc_[mf][nf], 0, 0, 0);                                                 \
    __builtin_amdgcn_s_setprio(0);                                                  \
  } while (0)

  s16x8 aA[4], aB[4], bA[4], bB[4];

  // prologue: 12 loads; vmcnt(4) drains h0(0)+h1(0), leaves h0(1) in flight
  stage_half(0, 0, 0); stage_half(0, 1, 0);
  stage_half(0, 0, 1); stage_half(0, 1, 1);
  stage_half(1, 0, 0); stage_half(1, 1, 0);
  asm volatile("s_waitcnt vmcnt(4)" ::: "memory");
  __builtin_amdgcn_s_barrier();
  READ_A(aA, 0, 0, 0);
  READ_B(bA, 0, 0);

  for (int kt = 0; kt < NKT; ++kt) {
    // p0: MFMA(aA,bA)->acc0; prefetch aB<-A(kt,0,1); stage A h1 kt+1
    READ_A(aB, kt, 0, 1);
    stage_half(kt + 1, 0, 1);
    MFMA16(acc[0], aA, bA);
    // p1: MFMA(aB,bA)->acc1; prefetch aA<-A(kt,1,0), bB<-B(kt,1); stage B h1 kt+1
    READ_A(aA, kt, 1, 0);
    READ_B(bB, kt, 1);
    stage_half(kt + 1, 1, 1);
    MFMA16(acc[1], aB, bA);
    asm volatile("s_waitcnt vmcnt(4)" ::: "memory");  // drains h0(kt+1)
    __builtin_amdgcn_s_barrier();
    // p2: MFMA(aA,bB)->acc0; prefetch aB<-A(kt,1,1); stage A h0 kt+2
    READ_A(aB, kt, 1, 1);
    stage_half(kt + 2, 0, 0);
    MFMA16(acc[0], aA, bB);
    // p3: MFMA(aB,bB)->acc1; prefetch aA<-A(kt+1,0,0), bA<-B(kt+1,0); stage B h0 kt+2
    READ_A(aA, kt + 1, 0, 0);
    READ_B(bA, kt + 1, 0);
    stage_half(kt + 2, 1, 0);
    MFMA16(acc[1], aB, bB);
    asm volatile("s_waitcnt vmcnt(4)" ::: "memory");  // drains h1(kt+1)
    __builtin_amdgcn_s_barrier();
  }
  asm volatile("s_waitcnt vmcnt(0)" ::: "memory");

  // epilogue: C/D layout col=lane&15, row=(lane>>4)*4+r
  int c0 = jb * 256 + wn * 64;
  int r0 = mb * 256 + wm * 128;
#pragma unroll
  for (int qm = 0; qm < 2; ++qm)
#pragma unroll
    for (int mf = 0; mf < 4; ++mf)
#pragma unroll
      for (int nf = 0; nf < 4; ++nf) {
        int c = c0 + nf * 16 + ml;
        if (c < NOUT) {
          int r = r0 + qm * 64 + mf * 16 + (lane >> 4) * 4;
#pragma unroll
          for (int i = 0; i < 4; ++i)
            Y[(size_t)(r + i) * NOUT + c] = acc[qm][mf][nf][i];
        }
      }
#undef READ_A
#undef READ_B
#undef MFMA16
}

extern "C" void kernel_launch(void* const* d_in, const int* in_sizes, int n_in,
                              void* d_out, int out_size, void* d_ws, size_t ws_size,
                              hipStream_t stream) {
  const float* X     = (const float*)d_in[0];
  const float* A     = (const float*)d_in[1];
  const float* alpha = (const float*)d_in[2];
  const float* beta0 = (const float*)d_in[3];
  const float* beta1 = (const float*)d_in[4];
  float* Y = (float*)d_out;
  char* ws = (char*)d_ws;
  char* Bpk = ws;                       // 64 MiB
  char* Apk = ws + APK_OFF;             // 4 MiB
  unsigned* B1 = (unsigned*)(ws + B1_OFF);

  k_masks<<<dim3(1024), dim3(256), 0, stream>>>(A, B1);
  k_wp<<<dim3(17408), dim3(256), 0, stream>>>(B1, alpha, beta0, beta1, X,
                                              (unsigned short*)Apk,
                                              (unsigned short*)Bpk);
  k_gemm<<<dim3(256), dim3(512), 0, stream>>>(Apk, Bpk, Y);
}